// Round 5
// baseline (262.835 us; speedup 1.0000x reference)
//
#include <hip/hip_runtime.h>
#include <math.h>

// LightGCN layer: out[v] = sum_{(u->v)} w * x[u], N=100K, E=1.6M, D=128, fp32.
//
// R13: R12 falsified the occupancy theory for gather: occ 30->57% with BW
// unchanged (3.4 TB/s, FETCH 375MB) => gather is rate-saturated on random
// 512B row fills (LLC->L2). Gather reverted to proven NPB=128 and frozen.
// Front-end is ~126us across THREE different designs; common invariant =
// 1.6M scattered 8B csr stores (each 64B line touched by ~2 blocks/XCDs ->
// write-allocate fetch + partial writeback per XCD, ~12.5% line efficiency).
// Fix: LINE-ALIGNED PADDED RUNS. Every per-(block,bucket) reservation is
// rounded up to 8 edges (64B); gap slots pre-filled with zero-edges
// (src=0,w=0 -> adds 0*x[0], harmless; dl cycled to avoid hot nodes).
// Each csr line is then written entirely by ONE block -> one allocate, one
// full-dirty writeback, no cross-XCD RMW.
//   - seg path (3 dispatches): init -> scatter(pad) -> gather
//   - exact path: memset -> hist(rounded counts, SAME tiling as scatter)
//     -> scatter(pad) -> gather; unpadded exact kept for small ws.

constexpr int D_FEAT = 128;
constexpr int NPB = 128;        // nodes per bucket (dst >> 7)
constexpr int LOG_NPB = 7;
constexpr int NBK_MAX = 1024;
constexpr int SCB = 128;        // scatter/hist block count (shared tiling!)
constexpr int CAP = 3072;       // max edges per bucket staged in gather LDS

typedef float v4f __attribute__((ext_vector_type(4)));

// ---------------- fallback (R1) ----------------
__global__ __launch_bounds__(256) void scatter_atomic_kernel(
    const float* __restrict__ x, const float* __restrict__ w,
    const int* __restrict__ src_idx, const int* __restrict__ dst_idx,
    float* __restrict__ out, int n_edges) {
  long long tid = (long long)blockIdx.x * blockDim.x + threadIdx.x;
  int lane = (int)(tid & 31);
  long long e = tid >> 5;
  if (e >= n_edges) return;
  int s = src_idx[e];
  int d = dst_idx[e];
  float wt = w[e];
  float4 v = ((const float4*)(x + (size_t)s * D_FEAT))[lane];
  float* o = out + (size_t)d * D_FEAT + (size_t)lane * 4;
  atomicAdd(o + 0, v.x * wt);
  atomicAdd(o + 1, v.y * wt);
  atomicAdd(o + 2, v.z * wt);
  atomicAdd(o + 3, v.w * wt);
}

// block-wide exclusive scan over blockDim.x threads (multiple of 64, <=512);
// sh holds >= (nwaves+1) ints (declare 9).
__device__ __forceinline__ int block_excl_scan(int v, int* sh, int* total) {
  const int lane = threadIdx.x & 63;
  const int wid = threadIdx.x >> 6;
  const int nw = blockDim.x >> 6;
  int inc = v;
  #pragma unroll
  for (int o = 1; o < 64; o <<= 1) {
    int t = __shfl_up(inc, o, 64);
    if (lane >= o) inc += t;
  }
  if (lane == 63) sh[wid] = inc;
  __syncthreads();
  if (threadIdx.x == 0) {
    int a = 0;
    for (int k = 0; k < nw; ++k) { int t = sh[k]; sh[k] = a; a += t; }
    sh[nw] = a;
  }
  __syncthreads();
  int r = sh[wid] + inc - v;
  if (total) *total = sh[nw];
  __syncthreads();
  return r;
}

// ---------------- exact path phase 1: global hist + in-kernel prefix -------
// Uses the SAME tiling as scatter (SCB blocks, tile edges) so that the
// per-(block,bucket) rounded counts match scatter's reservations exactly.
// gtot/gcur/done pre-zeroed by memset. Last block computes the exclusive
// prefix into gbase[0..nbk] and initializes gcur = gbase.
__global__ __launch_bounds__(512) void hist_kernel(
    const int* __restrict__ dst, int* __restrict__ gtot,
    int* __restrict__ gcur, int* __restrict__ gbase, int* __restrict__ done,
    int n_edges, int nbk, int tile, int pad8) {
  __shared__ int h[NBK_MAX];
  __shared__ int sh[9];
  __shared__ int slast;
  const int tid = threadIdx.x;
  const int b = blockIdx.x;
  for (int k = tid; k < nbk; k += 512) h[k] = 0;
  __syncthreads();
  int base = b * tile;
  int lim = min(base + tile, n_edges);
  for (int i = base + tid; i < lim; i += 512)
    atomicAdd(&h[((unsigned)dst[i]) >> LOG_NPB], 1);
  __syncthreads();
  for (int k = tid; k < nbk; k += 512) {
    int v = h[k];
    if (v) {
      int r = pad8 ? ((v + 7) & ~7) : v;
      atomicAdd(&gtot[k], r);
    }
  }
  __threadfence();
  __syncthreads();
  if (tid == 0)
    slast = (__hip_atomic_fetch_add(done, 1, __ATOMIC_ACQ_REL,
                                    __HIP_MEMORY_SCOPE_AGENT) ==
             (int)gridDim.x - 1);
  __syncthreads();
  if (slast) {
    int carry = 0;
    for (int kb = 0; kb < nbk; kb += 512) {
      int k = kb + tid;
      int v = (k < nbk)
                  ? __hip_atomic_load(&gtot[k], __ATOMIC_RELAXED,
                                      __HIP_MEMORY_SCOPE_AGENT)
                  : 0;
      int tot;
      int ex = block_excl_scan(v, sh, &tot);
      if (k < nbk) { gbase[k] = carry + ex; gcur[k] = carry + ex; }
      carry += tot;
    }
    if (tid == 0) gbase[nbk] = carry;
  }
}

// ---------------- segment path init: gcur[k] = k*capb ----------------------
__global__ __launch_bounds__(256) void init_seg_kernel(int* __restrict__ gcur,
                                                       int nbk, int capb) {
  int k = blockIdx.x * 256 + threadIdx.x;
  if (k < nbk) gcur[k] = k * capb;
}

// ---------------- phase 2: scatter with line-aligned padded runs -----------
// pass1: LDS hist of the tile. reserve: per non-empty bucket one global
// atomicAdd of the ROUNDED size r=(v+7)&~7 (runs stay 64B-aligned because
// bases are 8-aligned and all reservations are multiples of 8); gap slots
// [v,r) pre-filled with zero-edges. pass2: re-read (L2-warm) and place via
// LDS cursors. Every csr 64B line belongs to exactly one block.
// capb != 0 => segment mode: runs that would cross the segment end are
// dropped entirely (gb=-1); gather then sees cnt > capb -> raw-scan.
__global__ __launch_bounds__(512) void scatter_kernel(
    const int* __restrict__ src, const int* __restrict__ dst,
    const float* __restrict__ w, int* __restrict__ gcur,
    uint2* __restrict__ csr, int n_edges, int nbk, int tile, int capb,
    int pad8) {
  __shared__ int h[NBK_MAX];
  __shared__ int cur[NBK_MAX];
  __shared__ int gb[NBK_MAX];
  const int tid = threadIdx.x;
  const int b = blockIdx.x;
  int base = b * tile;
  int lim = min(base + tile, n_edges);
  for (int k = tid; k < nbk; k += 512) h[k] = 0;
  __syncthreads();
  for (int i = base + tid; i < lim; i += 512)
    atomicAdd(&h[((unsigned)dst[i]) >> LOG_NPB], 1);
  __syncthreads();
  for (int k = tid; k < nbk; k += 512) {
    cur[k] = 0;
    int v = h[k];
    if (v) {
      int r = pad8 ? ((v + 7) & ~7) : v;
      int g = atomicAdd(&gcur[k], r);
      if (capb && (g + r > (k + 1) * capb)) g = -1;  // dropped run
      gb[k] = g;
      if (g >= 0) {
        for (int p = v; p < r; ++p)  // zero-edge pads (dl cycled, w=0)
          csr[g + p] =
              make_uint2(((unsigned)(g + p) & (NPB - 1u)) << 20, 0u);
      }
    } else {
      gb[k] = -1;
    }
  }
  __syncthreads();
  for (int i = base + tid; i < lim; i += 512) {
    unsigned d = (unsigned)dst[i];
    unsigned k = d >> LOG_NPB;
    int pos = atomicAdd(&cur[k], 1);
    int g = gb[k];
    if (g >= 0)
      csr[g + pos] = make_uint2((unsigned)src[i] | ((d & (NPB - 1u)) << 20),
                                __float_as_uint(w[i]));
  }
}

// ---------------- phase 3: gather (LDS perm-sort + register accumulate) ----
// Frozen structure (R8/R12-proven, rate-saturated at ~3.4 TB/s).
__global__ __launch_bounds__(256) void gather_kernel(
    const float* __restrict__ x, const int* __restrict__ gbase,
    const int* __restrict__ gcur, const uint2* __restrict__ csr,
    float* __restrict__ out, int n_nodes, int capb,
    const int* __restrict__ src, const int* __restrict__ dst,
    const float* __restrict__ w, int n_edges) {
  __shared__ uint2 eds[CAP];            // 24 KB staged edges
  __shared__ unsigned short perm[CAP];  // 6 KB sorted order
  __shared__ int loff[NPB + 1];
  __shared__ int lcur[NPB];
  __shared__ int sh[9];

  const int b = blockIdx.x;
  const int tid = threadIdx.x;
  const int beg = capb ? b * capb : gbase[b];
  const int cnt = gcur[b] - beg;
  const int limcap = capb ? capb : CAP;
  const int nbase = b * NPB;

  const int wv = tid >> 6;
  const int lane = tid & 63;
  const int f = lane & 31;
  const int half = lane >> 5;
  const float4* X = (const float4*)x;

  if (cnt <= limcap) {
    // stage + local hist
    if (tid < NPB) lcur[tid] = 0;
    __syncthreads();
    for (int i = tid; i < cnt; i += 256) {
      uint2 e = csr[beg + i];
      eds[i] = e;
      atomicAdd(&lcur[e.x >> 20], 1);
    }
    __syncthreads();
    // scan 128 counters -> loff, reset lcur as cursor
    {
      int v = (tid < NPB) ? lcur[tid] : 0;
      int ex = block_excl_scan(v, sh, nullptr);
      __syncthreads();
      if (tid < NPB) { loff[tid] = ex; lcur[tid] = 0; }
      if (tid == 0) loff[NPB] = cnt;
    }
    __syncthreads();
    // build perm (counting-sort placement)
    for (int i = tid; i < cnt; i += 256) {
      int dl = eds[i].x >> 20;
      int pos = loff[dl] + atomicAdd(&lcur[dl], 1);
      perm[pos] = (unsigned short)i;
    }
    __syncthreads();

    // register-accumulate per node (1 wave/node, 2 halves x unroll4)
    for (int n = wv; n < NPB; n += 4) {
      int node = nbase + n;
      if (node >= n_nodes) break;
      int jb = loff[n];
      int je = loff[n + 1];
      float4 a0 = make_float4(0.f, 0.f, 0.f, 0.f);
      float4 a1 = make_float4(0.f, 0.f, 0.f, 0.f);
      float4 a2 = make_float4(0.f, 0.f, 0.f, 0.f);
      float4 a3 = make_float4(0.f, 0.f, 0.f, 0.f);
      int j = jb + half;
      for (; j + 6 < je; j += 8) {
        uint2 e0 = eds[perm[j]];
        uint2 e1 = eds[perm[j + 2]];
        uint2 e2 = eds[perm[j + 4]];
        uint2 e3 = eds[perm[j + 6]];
        float4 v0 = X[(size_t)(e0.x & 0xFFFFFu) * 32 + f];
        float4 v1 = X[(size_t)(e1.x & 0xFFFFFu) * 32 + f];
        float4 v2 = X[(size_t)(e2.x & 0xFFFFFu) * 32 + f];
        float4 v3 = X[(size_t)(e3.x & 0xFFFFFu) * 32 + f];
        float w0 = __uint_as_float(e0.y);
        float w1 = __uint_as_float(e1.y);
        float w2 = __uint_as_float(e2.y);
        float w3 = __uint_as_float(e3.y);
        a0.x += w0 * v0.x; a0.y += w0 * v0.y; a0.z += w0 * v0.z; a0.w += w0 * v0.w;
        a1.x += w1 * v1.x; a1.y += w1 * v1.y; a1.z += w1 * v1.z; a1.w += w1 * v1.w;
        a2.x += w2 * v2.x; a2.y += w2 * v2.y; a2.z += w2 * v2.z; a2.w += w2 * v2.w;
        a3.x += w3 * v3.x; a3.y += w3 * v3.y; a3.z += w3 * v3.z; a3.w += w3 * v3.w;
      }
      for (; j < je; j += 2) {
        uint2 e0 = eds[perm[j]];
        float4 v0 = X[(size_t)(e0.x & 0xFFFFFu) * 32 + f];
        float w0 = __uint_as_float(e0.y);
        a0.x += w0 * v0.x; a0.y += w0 * v0.y; a0.z += w0 * v0.z; a0.w += w0 * v0.w;
      }
      a0.x += a1.x + a2.x + a3.x;
      a0.y += a1.y + a2.y + a3.y;
      a0.z += a1.z + a2.z + a3.z;
      a0.w += a1.w + a2.w + a3.w;
      a0.x += __shfl_xor(a0.x, 32, 64);
      a0.y += __shfl_xor(a0.y, 32, 64);
      a0.z += __shfl_xor(a0.z, 32, 64);
      a0.w += __shfl_xor(a0.w, 32, 64);
      if (half == 0) {
        v4f val = {a0.x, a0.y, a0.z, a0.w};
        __builtin_nontemporal_store(val, (v4f*)out + (size_t)node * 32 + f);
      }
    }
  } else {
    // safety net (statistically unreachable; also covers segment overflow):
    // scan the RAW edge list for this bucket's nodes.
    for (int n = wv; n < NPB; n += 4) {
      int node = nbase + n;
      if (node >= n_nodes) break;
      float4 a0 = make_float4(0.f, 0.f, 0.f, 0.f);
      for (int j = half; j < n_edges; j += 2) {
        if (dst[j] == node) {
          float4 v = X[(size_t)src[j] * 32 + f];
          float wt = w[j];
          a0.x += wt * v.x; a0.y += wt * v.y; a0.z += wt * v.z; a0.w += wt * v.w;
        }
      }
      a0.x += __shfl_xor(a0.x, 32, 64);
      a0.y += __shfl_xor(a0.y, 32, 64);
      a0.z += __shfl_xor(a0.z, 32, 64);
      a0.w += __shfl_xor(a0.w, 32, 64);
      if (half == 0) {
        v4f val = {a0.x, a0.y, a0.z, a0.w};
        __builtin_nontemporal_store(val, (v4f*)out + (size_t)node * 32 + f);
      }
    }
  }
}

extern "C" void kernel_launch(void* const* d_in, const int* in_sizes, int n_in,
                              void* d_out, int out_size, void* d_ws, size_t ws_size,
                              hipStream_t stream) {
  const float* x  = (const float*)d_in[0];
  const float* w  = (const float*)d_in[1];
  const int* eidx = (const int*)d_in[2];

  int n_edges = in_sizes[1];           // E
  int n_nodes = out_size / D_FEAT;     // N
  const int* src = eidx;
  const int* dst = eidx + n_edges;
  float* out = (float*)d_out;

  if (n_edges <= 0) {
    hipMemsetAsync(d_out, 0, (size_t)out_size * sizeof(float), stream);
    return;
  }

  const int nbk = (n_nodes + NPB - 1) / NPB;       // buckets (782 @100K)
  const int stile = (n_edges + SCB - 1) / SCB;     // edges per tile (shared)

  // ws layout (ints): gtot[1024] | gcur[1024] | done[4] | gbase[1028] | csr
  const size_t ctrl_ints = (size_t)NBK_MAX + NBK_MAX + 4 + (NBK_MAX + 4);
  const size_t ctrl_bytes = ctrl_ints * 4;
  long long slots_avail = ((long long)ws_size - (long long)ctrl_bytes) / 8;

  long long mean = n_edges / (nbk > 0 ? nbk : 1);
  // padded segment sizing: true count tail (7 sigma) + pad mean (3.5/block)
  // + pad tail (8 sqrt(SCB)) + slack
  int capb_min = (int)(mean + 7.0 * sqrt((double)(mean > 0 ? mean : 1)) +
                       3.5 * SCB + 8.0 * sqrt((double)SCB) + 16);
  int capb = 0;
  if (nbk > 0 && slots_avail > 0) {
    long long c = slots_avail / nbk;
    if (c > CAP) c = CAP;
    capb = (int)(c & ~7LL);              // 64B-aligned segment starts
  }
  long long worst_pad = (long long)SCB * nbk * 7;
  bool seg_ok = (capb >= capb_min && capb_min <= CAP);
  bool exact_pad_ok = (slots_avail >= (long long)n_edges + worst_pad + 16);
  bool exact_ok = (slots_avail >= (long long)n_edges);

  if ((!seg_ok && !exact_ok) || nbk > NBK_MAX || n_nodes >= (1 << 20)) {
    hipMemsetAsync(d_out, 0, (size_t)out_size * sizeof(float), stream);
    long long total_threads = (long long)n_edges * 32;
    long long grid = (total_threads + 255) / 256;
    scatter_atomic_kernel<<<(dim3)(unsigned)grid, 256, 0, stream>>>(
        x, w, src, dst, out, n_edges);
    return;
  }

  int* gtot = (int*)d_ws;                   // 1024
  int* gcur = gtot + NBK_MAX;               // 1024
  int* done = gcur + NBK_MAX;               // 4
  int* gbase = done + 4;                    // 1028 (nbk+1 used)
  uint2* csr = (uint2*)(gbase + NBK_MAX + 4);

  if (seg_ok) {
    // 3 dispatches: init -> scatter(pad) -> gather
    init_seg_kernel<<<(nbk + 255) / 256, 256, 0, stream>>>(gcur, nbk, capb);
    scatter_kernel<<<SCB, 512, 0, stream>>>(src, dst, w, gcur, csr,
                                            n_edges, nbk, stile, capb, 1);
    gather_kernel<<<nbk, 256, 0, stream>>>(x, gbase, gcur, csr, out, n_nodes,
                                           capb, src, dst, w, n_edges);
  } else {
    // exact-CSR path: memset -> hist(+prefix) -> scatter -> gather
    int pad8 = exact_pad_ok ? 1 : 0;
    hipMemsetAsync(gtot, 0, (size_t)(NBK_MAX * 2 + 4) * sizeof(int), stream);
    hist_kernel<<<SCB, 512, 0, stream>>>(dst, gtot, gcur, gbase, done,
                                         n_edges, nbk, stile, pad8);
    scatter_kernel<<<SCB, 512, 0, stream>>>(src, dst, w, gcur, csr,
                                            n_edges, nbk, stile, 0, pad8);
    gather_kernel<<<nbk, 256, 0, stream>>>(x, gbase, gcur, csr, out, n_nodes,
                                           0, src, dst, w, n_edges);
  }
}